// Round 6
// baseline (437.619 us; speedup 1.0000x reference)
//
#include <hip/hip_runtime.h>
#include <stdint.h>

namespace {
constexpr int Bn  = 16;
constexpr int Cc  = 256;
constexpr int Hn  = 512;
constexpr int Tn  = 4096;
constexpr int CWn = Cc / 32;   // 8 words packed over C
constexpr int HWn = Hn / 32;   // 16 words packed over H
constexpr int TWn = Tn / 32;   // 128 words packed over T
constexpr int TC  = 64;        // t-chunk per fused block
constexpr float EPSf = 1e-5f;
}

// ---------------- setup: thresholds + packed sign weights --------------------
// thr = mean - beta*sqrt(var+eps)/gamma  (gamma>=0 => bn(v)>0 <=> v>thr;
// gamma==0 gives +-inf which selects the constant sign(beta) branch correctly)
__global__ __launch_bounds__(256) void setup_kernel(
    const float* __restrict__ bn1g, const float* __restrict__ bn1b,
    const float* __restrict__ bn1m, const float* __restrict__ bn1v,
    const float* __restrict__ w1,
    const float* __restrict__ bn2g, const float* __restrict__ bn2b,
    const float* __restrict__ bn2m, const float* __restrict__ bn2v,
    const float* __restrict__ dww,
    const float* __restrict__ bn3g, const float* __restrict__ bn3b,
    const float* __restrict__ bn3m, const float* __restrict__ bn3v,
    const float* __restrict__ w2,
    float* __restrict__ thr1, float* __restrict__ thr2, float* __restrict__ thr3,
    uint32_t* __restrict__ dws, uint32_t* __restrict__ W1p, uint32_t* __restrict__ W2p)
{
  const int idx = blockIdx.x * 256 + threadIdx.x;  // 65536 threads
  if (idx < 8 * Hn * CWn) {                        // W1 words: 32768
    const int w = idx & (CWn - 1);
    const int h = idx >> 3;                        // global h 0..4095
    const float* src = w1 + (size_t)h * Cc + w * 32;
    uint32_t word = 0;
#pragma unroll
    for (int j = 0; j < 32; ++j) word |= (uint32_t)(src[j] > 0.f) << j;
    W1p[h * CWn + w] = word;
  } else {                                         // W2 words: 32768
    const int k = idx - 8 * Hn * CWn;
    const int w = k & (HWn - 1);
    const int c = k >> 4;                          // global c 0..2047
    const float* src = w2 + (size_t)c * Hn + w * 32;
    uint32_t word = 0;
#pragma unroll
    for (int j = 0; j < 32; ++j) word |= (uint32_t)(src[j] > 0.f) << j;
    W2p[c * HWn + w] = word;
  }
  if (idx < 8 * Cc)
    thr1[idx] = bn1m[idx] - bn1b[idx] * sqrtf(bn1v[idx] + EPSf) / bn1g[idx];
  if (idx < 8 * Hn) {
    thr2[idx] = bn2m[idx] - bn2b[idx] * sqrtf(bn2v[idx] + EPSf) / bn2g[idx];
    thr3[idx] = bn3m[idx] - bn3b[idx] * sqrtf(bn3v[idx] + EPSf) / bn3g[idx];
    uint32_t dw = 0;
    for (int k = 0; k < 3; ++k) dw |= (uint32_t)(dww[(size_t)idx * 3 + k] > 0.f) << k;
    dws[idx] = dw;
  }
}

// --------------- K1: bn1 + sign + pack over C  (x -> Xp), i=0 only -----------
__global__ __launch_bounds__(256) void k1_pack(
    const float* __restrict__ resid, const float* __restrict__ thr1,
    uint32_t* __restrict__ Xp)
{
  const int idx = blockIdx.x * 256 + threadIdx.x;  // Bn*CWn*Tn threads
  const int t  = idx & (Tn - 1);
  const int cw = (idx >> 12) & (CWn - 1);
  const int b  = idx >> 15;
  const float* r = resid + ((size_t)(b * Cc + cw * 32)) * Tn + t;
  uint32_t word = 0;
#pragma unroll
  for (int j = 0; j < 32; ++j)
    word |= (uint32_t)(r[(size_t)j * Tn] > thr1[cw * 32 + j]) << j;
  Xp[((size_t)b * CWn + cw) * Tn + t] = word;
}

// --------- K2: binary GEMM1 (C->H) + bn2 + sign + pack over T (-> Y) ---------
// i=0 prologue only. Block-uniform (b, og, tblk) => W1 scalarizes to SGPRs.
// Y layout: [b][tw][h].
__global__ __launch_bounds__(256) void k2_gemm1(
    const uint32_t* __restrict__ Xp, const uint32_t* __restrict__ W1p,
    const float* __restrict__ thr2, uint32_t* __restrict__ Y)
{
  const int bid  = blockIdx.x;          // b(16) x og(64) x tblk(16)
  const int tblk = bid & 15;
  const int og   = (bid >> 4) & 63;
  const int b    = bid >> 10;
  const int t    = tblk * 256 + threadIdx.x;
  const int o    = og * 8;

  const uint32_t* xrow = Xp + (size_t)b * CWn * Tn + t;
  const uint32_t* wrow = W1p + o * CWn;     // uniform -> scalar loads
  int acc[8] = {0, 0, 0, 0, 0, 0, 0, 0};
#pragma unroll
  for (int w = 0; w < CWn; ++w) {
    const uint32_t xw = xrow[(size_t)w * Tn];
#pragma unroll
    for (int r = 0; r < 8; ++r)
      acc[r] += __popc(xw ^ wrow[r * CWn + w]);
  }
  const int lane = threadIdx.x & 63;
#pragma unroll
  for (int r = 0; r < 8; ++r) {
    const float v = (float)(Cc - 2 * acc[r]);
    const uint64_t m = __ballot(v > thr2[o + r]);   // bit l <-> lane l
    if ((lane & 31) == 0)
      Y[((size_t)b * TWn + (t >> 5)) * Hn + o + r] = (uint32_t)(m >> lane);
  }
}

// ---- K_iter: fused dwconv_i + GEMM2_i + residual + bn1/sign + GEMM1_{i+1} ----
// Block = 512 threads = (b, 64-t chunk); grid = 16*64 = 1024 blocks.
// Phase A: 8 waves x 2 tasks cover 16 hw; each half-wave does one 32ch x 32t
//          tile: majority-logic dwconv + 32x32 bit transpose -> Zlds[hw][tl].
// Phase B: wave = cw (readfirstlane => W2 in SGPRs), lane = t; H->C GEMM in
//          8-j chunks with all 8 rin loads issued before compute (latency
//          hiding); residual add (f32, reference order); bn1/sign -> Xlds.
// Phase C: wave covers 64 outs (8 rounds x 8); X from Xlds, W1 in SGPRs;
//          ballot-pack Y_next[b][tw][h].
__global__ __launch_bounds__(512) void k_iter(
    const uint32_t* __restrict__ Yin, const uint32_t* __restrict__ dws,
    const float* __restrict__ thr3, const uint32_t* __restrict__ W2p,
    const float* __restrict__ rin, float* __restrict__ rout,
    const float* __restrict__ thr1n, const uint32_t* __restrict__ W1n,
    const float* __restrict__ thr2n, uint32_t* __restrict__ Yout,
    int dil, int do_next)
{
  __shared__ uint32_t Zlds[HWn * TC];   // [hw][t_local], 4 KB
  __shared__ uint32_t Xlds[CWn * TC];   // [cw][t_local], 2 KB

  const int chunk = blockIdx.x & (Tn / TC - 1);   // 64 chunks
  const int b     = blockIdx.x >> 6;
  const int lane  = threadIdx.x & 63;
  const int wid   = __builtin_amdgcn_readfirstlane(threadIdx.x >> 6); // 0..7
  const int lh    = lane & 31;
  const int twL   = lane >> 5;                    // 0/1: which tw of the chunk
  const int tw0   = chunk * 2;                    // 2 tw per chunk

  // ---------------- Phase A: dwconv into Zlds ----------------
#pragma unroll
  for (int task = 0; task < 2; ++task) {
    const int hw = wid * 2 + task;                // 0..15
    const int tw = tw0 + twL;
    const int ch = hw * 32 + lh;

    const uint32_t* yb = Yin + (size_t)b * TWn * Hn + ch;
    const uint32_t ycur = yb[(size_t)tw * Hn];
    uint32_t yl, yr, Vl, Vr;
    if (dil >= 32) {
      const int dw = dil >> 5;
      const bool lok = tw >= dw, rok = tw + dw < TWn;
      yl = lok ? yb[(size_t)(tw - dw) * Hn] : 0u;
      yr = rok ? yb[(size_t)(tw + dw) * Hn] : 0u;
      Vl = lok ? ~0u : 0u;
      Vr = rok ? ~0u : 0u;
    } else {
      const uint32_t yp = (tw > 0) ? yb[(size_t)(tw - 1) * Hn] : 0u;
      const uint32_t yn = (tw < TWn - 1) ? yb[(size_t)(tw + 1) * Hn] : 0u;
      yl = (ycur << dil) | ((tw > 0) ? (yp >> (32 - dil)) : 0u);
      yr = (ycur >> dil) | ((tw < TWn - 1) ? (yn << (32 - dil)) : 0u);
      Vl = (tw == 0) ? (~0u << dil) : ~0u;
      Vr = (tw == TWn - 1) ? (~0u >> dil) : ~0u;
    }
    const uint32_t d = dws[ch];
    const uint32_t a  = ((d & 1u) ? yl : ~yl) & Vl;
    const uint32_t bb = (d & 2u) ? ycur : ~ycur;
    const uint32_t c  = ((d & 4u) ? yr : ~yr) & Vr;

    const float thr = thr3[ch];
    const float v3 = (thr + 3.f) * 0.5f;
    const float v2 = (thr + 2.f) * 0.5f;
    const int K3 = (int)(v3 >= 0.f) + (int)(v3 >= 1.f) + (int)(v3 >= 2.f) + (int)(v3 >= 3.f);
    const int K2 = (int)(v2 >= 0.f) + (int)(v2 >= 1.f) + (int)(v2 >= 2.f);

    const uint32_t g1 = a | bb | c;
    const uint32_t g2 = (a & bb) | (c & (a | bb));
    const uint32_t g3 = a & bb & c;
    const uint32_t full = (K3 == 0) ? ~0u : (K3 == 1) ? g1 : (K3 == 2) ? g2
                        : (K3 == 3) ? g3 : 0u;
    const uint32_t lm = (K2 == 0) ? ~0u : (K2 == 1) ? (bb | c) : (K2 == 2) ? (bb & c) : 0u;
    const uint32_t rm = (K2 == 0) ? ~0u : (K2 == 1) ? (a | bb) : (K2 == 2) ? (a & bb) : 0u;

    uint32_t w = (Vl & Vr & full) | (~Vl & lm) | (~Vr & rm);

    // 32x32 bit transpose within each 32-lane half (s<=16 stays in-half):
    // lane lh ends with word for t=tw*32+lh, bit j = channel hw*32+j.
#pragma unroll
    for (int s = 16; s; s >>= 1) {
      const uint32_t m = 0xFFFFFFFFu / ((1u << s) + 1u);
      const uint32_t o = __shfl_xor(w, s, 64);
      w = ((lane & s) == 0) ? ((w & m) | ((o & m) << s))
                            : ((w & ~m) | ((o & ~m) >> s));
    }
    Zlds[hw * TC + twL * 32 + lh] = w;
  }
  __syncthreads();

  // ------ Phase B: H->C GEMM + residual + bn1/sign for next block ------
  {
    const int cw = wid;                 // SGPR (readfirstlane above)
    const int tl = lane;
    const int tg = chunk * TC + tl;

    uint32_t z[HWn];
#pragma unroll
    for (int w = 0; w < HWn; ++w) z[w] = Zlds[w * TC + tl];

    const uint32_t* wrow = W2p + (cw * 32) * HWn;   // uniform -> scalar loads
    const size_t base = ((size_t)(b * Cc + cw * 32)) * Tn + tg;
    const float* rp = rin + base;
    float* op = rout + base;
    uint32_t word = 0;
#pragma unroll 1
    for (int jo = 0; jo < 32; jo += 8) {
      // issue all 8 residual loads first: 8 VMEM in flight under the VALU work
      float rv[8];
#pragma unroll
      for (int jj = 0; jj < 8; ++jj)
        rv[jj] = rp[(size_t)(jo + jj) * Tn];
#pragma unroll
      for (int jj = 0; jj < 8; ++jj) {
        const int j = jo + jj;
        int acc = 0;
#pragma unroll
        for (int w = 0; w < HWn; ++w) acc += __popc(z[w] ^ wrow[j * HWn + w]);
        const float ro = rv[jj] + (float)(Hn - 2 * acc);
        op[(size_t)j * Tn] = ro;
        word |= (uint32_t)(ro > thr1n[cw * 32 + j]) << j;
      }
    }
    Xlds[cw * TC + tl] = word;
  }
  __syncthreads();

  // ------ Phase C: GEMM1 for next block (C->H) -> Yout bits ------
  if (do_next) {
    const int t  = chunk * TC + lane;
    uint32_t x[CWn];
#pragma unroll
    for (int w = 0; w < CWn; ++w) x[w] = Xlds[w * TC + lane];

    uint32_t* yo = Yout + ((size_t)b * TWn + (t >> 5)) * Hn;
#pragma unroll 1
    for (int r = 0; r < 8; ++r) {
      const int o = wid * 64 + r * 8;               // SGPR-uniform
      const uint32_t* wrow = W1n + o * CWn;         // -> scalar loads
      int acc[8] = {0, 0, 0, 0, 0, 0, 0, 0};
#pragma unroll
      for (int w = 0; w < CWn; ++w) {
        const uint32_t xw = x[w];
#pragma unroll
        for (int q = 0; q < 8; ++q)
          acc[q] += __popc(xw ^ wrow[q * CWn + w]);
      }
#pragma unroll
      for (int q = 0; q < 8; ++q) {
        const float v = (float)(Cc - 2 * acc[q]);
        const uint64_t m = __ballot(v > thr2n[o + q]);
        if ((lane & 31) == 0)
          yo[o + q] = (uint32_t)(m >> lane);
      }
    }
  }
}

// ----------------------------------------------------------------------------
extern "C" void kernel_launch(void* const* d_in, const int* in_sizes, int n_in,
                              void* d_out, int out_size, void* d_ws, size_t ws_size,
                              hipStream_t stream)
{
  const float* x     = (const float*)d_in[0];
  const float* bn1g  = (const float*)d_in[1];
  const float* bn1b  = (const float*)d_in[2];
  const float* bn1m  = (const float*)d_in[3];
  const float* bn1v  = (const float*)d_in[4];
  const float* w1    = (const float*)d_in[5];
  const float* bn2g  = (const float*)d_in[6];
  const float* bn2b  = (const float*)d_in[7];
  const float* bn2m  = (const float*)d_in[8];
  const float* bn2v  = (const float*)d_in[9];
  const float* dww   = (const float*)d_in[10];
  const float* bn3g  = (const float*)d_in[11];
  const float* bn3b  = (const float*)d_in[12];
  const float* bn3m  = (const float*)d_in[13];
  const float* bn3v  = (const float*)d_in[14];
  const float* w2    = (const float*)d_in[15];
  float* out = (float*)d_out;

  // workspace carve-up (~10.6 MB total)
  char* ws = (char*)d_ws;
  uint32_t* Xp  = (uint32_t*)(ws);                        // 2 MB (prologue only)
  uint32_t* Ya  = (uint32_t*)(ws + (2u  << 20));          // 4 MB  [b][tw][h]
  uint32_t* Yb  = (uint32_t*)(ws + (6u  << 20));          // 4 MB  [b][tw][h]
  uint32_t* W1p = (uint32_t*)(ws + (10u << 20));          // 128 KB
  uint32_t* W2p = (uint32_t*)(ws + (10u << 20) + (128u << 10)); // 128 KB
  float*    thr1 = (float*)(ws + (10u << 20) + (256u << 10));
  float*    thr2 = thr1 + 8 * Cc;
  float*    thr3 = thr2 + 8 * Hn;
  uint32_t* dws  = (uint32_t*)(thr3 + 8 * Hn);

  setup_kernel<<<256, 256, 0, stream>>>(bn1g, bn1b, bn1m, bn1v, w1,
                                        bn2g, bn2b, bn2m, bn2v, dww,
                                        bn3g, bn3b, bn3m, bn3v, w2,
                                        thr1, thr2, thr3, dws, W1p, W2p);

  k1_pack <<<2048,  256, 0, stream>>>(x, thr1, Xp);
  k2_gemm1<<<16384, 256, 0, stream>>>(Xp, W1p, thr2, Ya);

  for (int i = 0; i < 8; ++i) {
    const float* rin = (i == 0) ? x : out;
    const int inext = (i < 7) ? i + 1 : 7;
    const uint32_t* Yin  = (i & 1) ? Yb : Ya;
    uint32_t*       Yout = (i & 1) ? Ya : Yb;
    k_iter<<<1024, 512, 0, stream>>>(Yin, dws + i * Hn, thr3 + i * Hn,
                                     W2p + i * Cc * HWn, rin, out,
                                     thr1 + inext * Cc, W1p + inext * Hn * CWn,
                                     thr2 + inext * Hn, Yout,
                                     1 << i, (i < 7) ? 1 : 0);
  }
}

// Round 7
// 382.239 us; speedup vs baseline: 1.1449x; 1.1449x over previous
//
#include <hip/hip_runtime.h>
#include <stdint.h>

namespace {
constexpr int Bn  = 16;
constexpr int Cc  = 256;
constexpr int Hn  = 512;
constexpr int Tn  = 4096;
constexpr int CWn = Cc / 32;   // 8 words packed over C
constexpr int HWn = Hn / 32;   // 16 words packed over H
constexpr int TWn = Tn / 32;   // 128 words packed over T
constexpr int TC  = 64;        // t-chunk per fused block
constexpr float EPSf = 1e-5f;
}

typedef __attribute__((ext_vector_type(4)))  int i32x4;
typedef __attribute__((ext_vector_type(16))) int i32x16;

// ---------------- setup: thresholds + packed/unpacked sign weights -----------
// thr = mean - beta*sqrt(var+eps)/gamma  (gamma>=0 => bn(v)>0 <=> v>thr)
// Also: W1u = {0,1} bytes of sign(w1)>0, K-swizzled (k ^= (h&15)<<4) for LDS;
//       Sw1[h] = sum of w1 bits (global atomicAdd, zeroed by memset each call);
//       T2i[h] = smallest integer strictly greater than thr2 (inf/NaN clamped).
__global__ __launch_bounds__(256) void setup_kernel(
    const float* __restrict__ bn1g, const float* __restrict__ bn1b,
    const float* __restrict__ bn1m, const float* __restrict__ bn1v,
    const float* __restrict__ w1,
    const float* __restrict__ bn2g, const float* __restrict__ bn2b,
    const float* __restrict__ bn2m, const float* __restrict__ bn2v,
    const float* __restrict__ dww,
    const float* __restrict__ bn3g, const float* __restrict__ bn3b,
    const float* __restrict__ bn3m, const float* __restrict__ bn3v,
    const float* __restrict__ w2,
    float* __restrict__ thr1, float* __restrict__ thr2, float* __restrict__ thr3,
    uint32_t* __restrict__ dws, uint32_t* __restrict__ W1p, uint32_t* __restrict__ W2p,
    uint8_t* __restrict__ W1u, int* __restrict__ Sw1, int* __restrict__ T2i)
{
  const int idx = blockIdx.x * 256 + threadIdx.x;  // 65536 threads
  if (idx < 8 * Hn * CWn) {                        // W1 words: 32768
    const int w = idx & (CWn - 1);
    const int h = idx >> 3;                        // global h 0..4095
    const float* src = w1 + (size_t)h * Cc + w * 32;
    uint32_t word = 0;
#pragma unroll
    for (int j = 0; j < 32; ++j) word |= (uint32_t)(src[j] > 0.f) << j;
    W1p[h * CWn + w] = word;
    atomicAdd(&Sw1[h], (int)__popc(word));
    // unpack to {0,1} bytes, swizzled:  W1u[h*256 + ((w*32+4q) ^ ((h&15)<<4))]
    uint32_t* dst = (uint32_t*)(W1u + (size_t)h * 256);
#pragma unroll
    for (int q = 0; q < 8; ++q) {
      const uint32_t dw = (((word >> (4 * q)) & 0xFu) * 0x00204081u) & 0x01010101u;
      const int off = (w * 32 + q * 4) ^ ((h & 15) << 4);
      dst[off >> 2] = dw;
    }
  } else {                                         // W2 words: 32768
    const int k = idx - 8 * Hn * CWn;
    const int w = k & (HWn - 1);
    const int c = k >> 4;                          // global c 0..2047
    const float* src = w2 + (size_t)c * Hn + w * 32;
    uint32_t word = 0;
#pragma unroll
    for (int j = 0; j < 32; ++j) word |= (uint32_t)(src[j] > 0.f) << j;
    W2p[c * HWn + w] = word;
  }
  if (idx < 8 * Cc)
    thr1[idx] = bn1m[idx] - bn1b[idx] * sqrtf(bn1v[idx] + EPSf) / bn1g[idx];
  if (idx < 8 * Hn) {
    const float th2 = bn2m[idx] - bn2b[idx] * sqrtf(bn2v[idx] + EPSf) / bn2g[idx];
    thr2[idx] = th2;
    int T;
    if (th2 >= 8.0e6f)       T =  (1 << 24);   // +inf / huge -> never exceed
    else if (th2 <= -8.0e6f) T = -(1 << 24);   // -inf -> always
    else if (th2 == th2)     T = (int)floorf(th2) + 1;  // strict ceil
    else                     T =  (1 << 24);   // NaN -> compare always false
    T2i[idx] = T;
    thr3[idx] = bn3m[idx] - bn3b[idx] * sqrtf(bn3v[idx] + EPSf) / bn3g[idx];
    uint32_t dw = 0;
    for (int k2 = 0; k2 < 3; ++k2) dw |= (uint32_t)(dww[(size_t)idx * 3 + k2] > 0.f) << k2;
    dws[idx] = dw;
  }
}

// --------------- K1: bn1 + sign + pack over C  (x -> Xp), i=0 only -----------
__global__ __launch_bounds__(256) void k1_pack(
    const float* __restrict__ resid, const float* __restrict__ thr1,
    uint32_t* __restrict__ Xp)
{
  const int idx = blockIdx.x * 256 + threadIdx.x;  // Bn*CWn*Tn threads
  const int t  = idx & (Tn - 1);
  const int cw = (idx >> 12) & (CWn - 1);
  const int b  = idx >> 15;
  const float* r = resid + ((size_t)(b * Cc + cw * 32)) * Tn + t;
  uint32_t word = 0;
#pragma unroll
  for (int j = 0; j < 32; ++j)
    word |= (uint32_t)(r[(size_t)j * Tn] > thr1[cw * 32 + j]) << j;
  Xp[((size_t)b * CWn + cw) * Tn + t] = word;
}

// --------- K2: binary GEMM1 (C->H) + bn2 + sign + pack over T (-> Y) ---------
// i=0 prologue only (popcount path). Y layout: [b][tw][h].
__global__ __launch_bounds__(256) void k2_gemm1(
    const uint32_t* __restrict__ Xp, const uint32_t* __restrict__ W1p,
    const float* __restrict__ thr2, uint32_t* __restrict__ Y)
{
  const int bid  = blockIdx.x;          // b(16) x og(64) x tblk(16)
  const int tblk = bid & 15;
  const int og   = (bid >> 4) & 63;
  const int b    = bid >> 10;
  const int t    = tblk * 256 + threadIdx.x;
  const int o    = og * 8;

  const uint32_t* xrow = Xp + (size_t)b * CWn * Tn + t;
  const uint32_t* wrow = W1p + o * CWn;     // uniform -> scalar loads
  int acc[8] = {0, 0, 0, 0, 0, 0, 0, 0};
#pragma unroll
  for (int w = 0; w < CWn; ++w) {
    const uint32_t xw = xrow[(size_t)w * Tn];
#pragma unroll
    for (int r = 0; r < 8; ++r)
      acc[r] += __popc(xw ^ wrow[r * CWn + w]);
  }
  const int lane = threadIdx.x & 63;
#pragma unroll
  for (int r = 0; r < 8; ++r) {
    const float v = (float)(Cc - 2 * acc[r]);
    const uint64_t m = __ballot(v > thr2[o + r]);   // bit l <-> lane l
    if ((lane & 31) == 0)
      Y[((size_t)b * TWn + (t >> 5)) * Hn + o + r] = (uint32_t)(m >> lane);
  }
}

// ---- K_iter: dwconv_i + GEMM2_i + residual + bn1/sign + MFMA-GEMM1_{i+1} ----
// Block = 512 threads = (b, 64-t chunk); grid = 1024 blocks.
// Phase A: majority-logic dwconv + 32x32 bit transpose -> Zlds[hw][tl] (packed)
// Phase B: wave = cw; H->C popcount GEMM (W2 in SGPRs); residual f32 add;
//          bn1/sign -> {0,1} bytes into Xi8[t][k^swz] + Sx[t] LDS atomics.
// Phase C: GEMM1 via v_mfma_i32_32x32x32_i8 on {0,1} operands.
//          out = 4S - 2Sx(t) - 2Sw(o) + 256; bit = (4S >= Tc[o] + 2Sx(t)),
//          Tc[o] = T2i[o] + 2*Sw1[o] - 256 (all-integer, exact).
__global__ __launch_bounds__(512) void k_iter(
    const uint32_t* __restrict__ Yin, const uint32_t* __restrict__ dws,
    const float* __restrict__ thr3, const uint32_t* __restrict__ W2p,
    const float* __restrict__ rin, float* __restrict__ rout,
    const float* __restrict__ thr1n,
    const uint8_t* __restrict__ W1u_n, const int* __restrict__ Sw1_n,
    const int* __restrict__ T2i_n, uint32_t* __restrict__ Yout,
    int dil, int do_next)
{
  __shared__ uint32_t Zlds[HWn * TC];                 // 4 KB packed Z
  __shared__ __align__(16) uint8_t Xi8[TC * 256];     // 16 KB {0,1}, [t][k^swz]
  __shared__ __align__(16) uint8_t Wbuf[128 * 256];   // 32 KB W1u supertile
  __shared__ int Sx[TC];                              // per-t popcount of x
  __shared__ int Tc[Hn];                              // integer thresholds

  const int chunk = blockIdx.x & (Tn / TC - 1);   // 64 chunks
  const int b     = blockIdx.x >> 6;
  const int tid   = threadIdx.x;
  const int lane  = tid & 63;
  const int wid   = __builtin_amdgcn_readfirstlane(tid >> 6); // 0..7
  const int lh    = lane & 31;
  const int twL   = lane >> 5;
  const int tw0   = chunk * 2;

  if (tid < TC) Sx[tid] = 0;

  // ---------------- Phase A: dwconv into Zlds (packed) ----------------
#pragma unroll
  for (int task = 0; task < 2; ++task) {
    const int hw = wid * 2 + task;                // 0..15
    const int tw = tw0 + twL;
    const int ch = hw * 32 + lh;

    const uint32_t* yb = Yin + (size_t)b * TWn * Hn + ch;
    const uint32_t ycur = yb[(size_t)tw * Hn];
    uint32_t yl, yr, Vl, Vr;
    if (dil >= 32) {
      const int dw = dil >> 5;
      const bool lok = tw >= dw, rok = tw + dw < TWn;
      yl = lok ? yb[(size_t)(tw - dw) * Hn] : 0u;
      yr = rok ? yb[(size_t)(tw + dw) * Hn] : 0u;
      Vl = lok ? ~0u : 0u;
      Vr = rok ? ~0u : 0u;
    } else {
      const uint32_t yp = (tw > 0) ? yb[(size_t)(tw - 1) * Hn] : 0u;
      const uint32_t yn = (tw < TWn - 1) ? yb[(size_t)(tw + 1) * Hn] : 0u;
      yl = (ycur << dil) | ((tw > 0) ? (yp >> (32 - dil)) : 0u);
      yr = (ycur >> dil) | ((tw < TWn - 1) ? (yn << (32 - dil)) : 0u);
      Vl = (tw == 0) ? (~0u << dil) : ~0u;
      Vr = (tw == TWn - 1) ? (~0u >> dil) : ~0u;
    }
    const uint32_t d = dws[ch];
    const uint32_t a  = ((d & 1u) ? yl : ~yl) & Vl;
    const uint32_t bb = (d & 2u) ? ycur : ~ycur;
    const uint32_t c  = ((d & 4u) ? yr : ~yr) & Vr;

    const float thr = thr3[ch];
    const float v3 = (thr + 3.f) * 0.5f;
    const float v2 = (thr + 2.f) * 0.5f;
    const int K3 = (int)(v3 >= 0.f) + (int)(v3 >= 1.f) + (int)(v3 >= 2.f) + (int)(v3 >= 3.f);
    const int K2 = (int)(v2 >= 0.f) + (int)(v2 >= 1.f) + (int)(v2 >= 2.f);

    const uint32_t g1 = a | bb | c;
    const uint32_t g2 = (a & bb) | (c & (a | bb));
    const uint32_t g3 = a & bb & c;
    const uint32_t full = (K3 == 0) ? ~0u : (K3 == 1) ? g1 : (K3 == 2) ? g2
                        : (K3 == 3) ? g3 : 0u;
    const uint32_t lm = (K2 == 0) ? ~0u : (K2 == 1) ? (bb | c) : (K2 == 2) ? (bb & c) : 0u;
    const uint32_t rm = (K2 == 0) ? ~0u : (K2 == 1) ? (a | bb) : (K2 == 2) ? (a & bb) : 0u;

    uint32_t w = (Vl & Vr & full) | (~Vl & lm) | (~Vr & rm);

    // 32x32 bit transpose within each 32-lane half.
#pragma unroll
    for (int s = 16; s; s >>= 1) {
      const uint32_t m = 0xFFFFFFFFu / ((1u << s) + 1u);
      const uint32_t o = __shfl_xor(w, s, 64);
      w = ((lane & s) == 0) ? ((w & m) | ((o & m) << s))
                            : ((w & ~m) | ((o & ~m) >> s));
    }
    Zlds[hw * TC + twL * 32 + lh] = w;
  }
  __syncthreads();

  // ------ Phase B: H->C GEMM + residual + bn1/sign (bytes + Sx) ------
  {
    const int cw = wid;
    const int tl = lane;
    const int tg = chunk * TC + tl;

    uint32_t z[HWn];
#pragma unroll
    for (int w = 0; w < HWn; ++w) z[w] = Zlds[w * TC + tl];

    const uint32_t* wrow = W2p + (cw * 32) * HWn;   // uniform -> scalar loads
    const size_t base = ((size_t)(b * Cc + cw * 32)) * Tn + tg;
    const float* rp = rin + base;
    float* op = rout + base;
    const int swz = (tl & 15) << 4;
    uint32_t word = 0;
#pragma unroll 1
    for (int jo = 0; jo < 32; jo += 8) {
      float rv[8];
#pragma unroll
      for (int jj = 0; jj < 8; ++jj)
        rv[jj] = rp[(size_t)(jo + jj) * Tn];
      uint32_t blo = 0, bhi = 0;
#pragma unroll
      for (int jj = 0; jj < 8; ++jj) {
        const int j = jo + jj;
        int acc = 0;
#pragma unroll
        for (int w = 0; w < HWn; ++w) acc += __popc(z[w] ^ wrow[j * HWn + w]);
        const float ro = rv[jj] + (float)(Hn - 2 * acc);
        op[(size_t)j * Tn] = ro;
        const uint32_t bit = (uint32_t)(ro > thr1n[cw * 32 + j]);
        word |= bit << j;
        if (jj < 4) blo |= bit << (jj * 8);
        else        bhi |= bit << ((jj - 4) * 8);
      }
      const int c0 = cw * 32 + jo;                 // multiple of 8
      *(uint32_t*)&Xi8[tl * 256 + (c0 ^ swz)]     = blo;
      *(uint32_t*)&Xi8[tl * 256 + (c0 ^ swz) + 4] = bhi;
    }
    atomicAdd(&Sx[tl], (int)__popc(word));
  }
  __syncthreads();

  // ------ Phase C: MFMA GEMM1 (C->H, {0,1} i8) -> Yout bits ------
  if (do_next) {
    // integer thresholds into LDS (one per thread)
    Tc[tid] = T2i_n[tid] + 2 * Sw1_n[tid] - 256;

    const int ntile = wid & 1;                    // which 32-t half
    const int mloc  = wid >> 1;                   // 0..3: 32-row tile in 128
    const int tloc  = ntile * 32 + (lane & 31);
    const int half  = lane >> 5;

    // B fragments (X): lane holds X[t=tloc][k = ks*32 + half*16 .. +15]
    i32x4 bf[8];
#pragma unroll
    for (int ks = 0; ks < 8; ++ks) {
      const int koff = (ks * 32 + half * 16) ^ ((tloc & 15) << 4);
      bf[ks] = *(const i32x4*)&Xi8[tloc * 256 + koff];
    }
    const int Sxv2 = 2 * Sx[tloc];
    uint32_t* yo = Yout + ((size_t)b * TWn + (chunk * 2 + ntile)) * Hn;

#pragma unroll 1
    for (int msup = 0; msup < 4; ++msup) {
      // stage 128x256 {0,1} supertile of W1u (already swizzle-stored)
      const uint32_t* gsrc = (const uint32_t*)(W1u_n + msup * 32768);
      uint32_t* ldst = (uint32_t*)Wbuf;
      i32x4 stg[4];
#pragma unroll
      for (int s = 0; s < 4; ++s)
        stg[s] = *(const i32x4*)&gsrc[(s * 512 + tid) * 4];
#pragma unroll
      for (int s = 0; s < 4; ++s)
        *(i32x4*)&ldst[(s * 512 + tid) * 4] = stg[s];
      __syncthreads();

      const int lrow = mloc * 32 + (lane & 31);
      i32x16 acc = {0,0,0,0, 0,0,0,0, 0,0,0,0, 0,0,0,0};
#pragma unroll
      for (int ks = 0; ks < 8; ++ks) {
        const int aoff = (ks * 32 + half * 16) ^ ((lrow & 15) << 4);
        const i32x4 af = *(const i32x4*)&Wbuf[lrow * 256 + aoff];
        acc = __builtin_amdgcn_mfma_i32_32x32x32_i8(af, bf[ks], acc, 0, 0, 0);
      }

      const int obase = msup * 128 + mloc * 32;
#pragma unroll
      for (int r = 0; r < 16; ++r) {
        const int row = (r & 3) + 8 * (r >> 2) + 4 * half;
        const int o = obase + row;
        const uint64_t m = __ballot((acc[r] << 2) >= Tc[o] + Sxv2);
        if ((lane & 31) == 0) yo[o] = (uint32_t)(m >> lane);
      }
      __syncthreads();
    }
  }
}

// ----------------------------------------------------------------------------
extern "C" void kernel_launch(void* const* d_in, const int* in_sizes, int n_in,
                              void* d_out, int out_size, void* d_ws, size_t ws_size,
                              hipStream_t stream)
{
  const float* x     = (const float*)d_in[0];
  const float* bn1g  = (const float*)d_in[1];
  const float* bn1b  = (const float*)d_in[2];
  const float* bn1m  = (const float*)d_in[3];
  const float* bn1v  = (const float*)d_in[4];
  const float* w1    = (const float*)d_in[5];
  const float* bn2g  = (const float*)d_in[6];
  const float* bn2b  = (const float*)d_in[7];
  const float* bn2m  = (const float*)d_in[8];
  const float* bn2v  = (const float*)d_in[9];
  const float* dww   = (const float*)d_in[10];
  const float* bn3g  = (const float*)d_in[11];
  const float* bn3b  = (const float*)d_in[12];
  const float* bn3m  = (const float*)d_in[13];
  const float* bn3v  = (const float*)d_in[14];
  const float* w2    = (const float*)d_in[15];
  float* out = (float*)d_out;

  // workspace carve-up (~12.1 MB total)
  char* ws = (char*)d_ws;
  uint32_t* Xp  = (uint32_t*)(ws);                        // 2 MB (prologue)
  uint32_t* Ya  = (uint32_t*)(ws + (2u  << 20));          // 4 MB  [b][tw][h]
  uint32_t* Yb  = (uint32_t*)(ws + (6u  << 20));          // 4 MB  [b][tw][h]
  uint32_t* W1p = (uint32_t*)(ws + (10u << 20));          // 128 KB (packed)
  uint32_t* W2p = (uint32_t*)(ws + (10u << 20) + (128u << 10)); // 128 KB
  float*    thr1 = (float*)(ws + (10u << 20) + (256u << 10));   // 8 KB
  float*    thr2 = thr1 + 8 * Cc;                               // 16 KB
  float*    thr3 = thr2 + 8 * Hn;                               // 16 KB
  uint32_t* dws  = (uint32_t*)(thr3 + 8 * Hn);                  // 16 KB
  uint8_t*  W1u  = (uint8_t*)(ws + (11u << 20));          // 1 MB {0,1} swizzled
  int*      Sw1  = (int*)(ws + (12u << 20));              // 16 KB
  int*      T2i  = (int*)(ws + (12u << 20) + (16u << 10));// 16 KB

  hipMemsetAsync(Sw1, 0, 8 * Hn * sizeof(int), stream);

  setup_kernel<<<256, 256, 0, stream>>>(bn1g, bn1b, bn1m, bn1v, w1,
                                        bn2g, bn2b, bn2m, bn2v, dww,
                                        bn3g, bn3b, bn3m, bn3v, w2,
                                        thr1, thr2, thr3, dws, W1p, W2p,
                                        W1u, Sw1, T2i);

  k1_pack <<<2048,  256, 0, stream>>>(x, thr1, Xp);
  k2_gemm1<<<16384, 256, 0, stream>>>(Xp, W1p, thr2, Ya);

  for (int i = 0; i < 8; ++i) {
    const float* rin = (i == 0) ? x : out;
    const int inext = (i < 7) ? i + 1 : 7;
    const uint32_t* Yin  = (i & 1) ? Yb : Ya;
    uint32_t*       Yout = (i & 1) ? Ya : Yb;
    k_iter<<<1024, 512, 0, stream>>>(Yin, dws + i * Hn, thr3 + i * Hn,
                                     W2p + i * Cc * HWn, rin, out,
                                     thr1 + inext * Cc,
                                     W1u + (size_t)inext * Hn * 256,
                                     Sw1 + inext * Hn, T2i + inext * Hn,
                                     Yout, 1 << i, (i < 7) ? 1 : 0);
  }
}

// Round 8
// 376.817 us; speedup vs baseline: 1.1614x; 1.0144x over previous
//
#include <hip/hip_runtime.h>
#include <stdint.h>

namespace {
constexpr int Bn  = 16;
constexpr int Cc  = 256;
constexpr int Hn  = 512;
constexpr int Tn  = 4096;
constexpr int CWn = Cc / 32;   // 8 words packed over C
constexpr int HWn = Hn / 32;   // 16 words packed over H
constexpr int TWn = Tn / 32;   // 128 words packed over T
constexpr int TC  = 64;        // t-chunk per fused block
constexpr float EPSf = 1e-5f;
}

typedef __attribute__((ext_vector_type(4)))  int i32x4;
typedef __attribute__((ext_vector_type(16))) int i32x16;

// ---------------- setup: thresholds + packed/unpacked sign weights -----------
// thr = mean - beta*sqrt(var+eps)/gamma  (gamma>=0 => bn(v)>0 <=> v>thr)
// W1u : {0,1} bytes of sign(w1)>0, K-swizzled (k ^= (h&15)<<4) for LDS staging.
// W2uf: {0,1} bytes of sign(w2)>0 in MFMA-fragment-major layout
//       [ks(16)][half(2)][c(256)][16B] per repeat-block (128 KB each).
// Sw1[h], Sw2[c]: row bit-counts (global atomicAdd, memset-zeroed each call).
// T2i[h]: smallest integer strictly greater than thr2 (inf/NaN clamped).
__global__ __launch_bounds__(256) void setup_kernel(
    const float* __restrict__ bn1g, const float* __restrict__ bn1b,
    const float* __restrict__ bn1m, const float* __restrict__ bn1v,
    const float* __restrict__ w1,
    const float* __restrict__ bn2g, const float* __restrict__ bn2b,
    const float* __restrict__ bn2m, const float* __restrict__ bn2v,
    const float* __restrict__ dww,
    const float* __restrict__ bn3g, const float* __restrict__ bn3b,
    const float* __restrict__ bn3m, const float* __restrict__ bn3v,
    const float* __restrict__ w2,
    float* __restrict__ thr1, float* __restrict__ thr2, float* __restrict__ thr3,
    uint32_t* __restrict__ dws, uint32_t* __restrict__ W1p,
    uint8_t* __restrict__ W1u, int* __restrict__ Sw1, int* __restrict__ T2i,
    uint8_t* __restrict__ W2uf, int* __restrict__ Sw2)
{
  const int idx = blockIdx.x * 256 + threadIdx.x;  // 65536 threads
  if (idx < 8 * Hn * CWn) {                        // W1 words: 32768
    const int w = idx & (CWn - 1);
    const int h = idx >> 3;                        // global h 0..4095
    const float* src = w1 + (size_t)h * Cc + w * 32;
    uint32_t word = 0;
#pragma unroll
    for (int j = 0; j < 32; ++j) word |= (uint32_t)(src[j] > 0.f) << j;
    W1p[h * CWn + w] = word;
    atomicAdd(&Sw1[h], (int)__popc(word));
    // unpack to {0,1} bytes, swizzled:  W1u[h*256 + ((w*32+4q) ^ ((h&15)<<4))]
    uint32_t* dst = (uint32_t*)(W1u + (size_t)h * 256);
#pragma unroll
    for (int q = 0; q < 8; ++q) {
      const uint32_t dw = (((word >> (4 * q)) & 0xFu) * 0x00204081u) & 0x01010101u;
      const int off = (w * 32 + q * 4) ^ ((h & 15) << 4);
      dst[off >> 2] = dw;
    }
  } else {                                         // W2 words: 32768
    const int k = idx - 8 * Hn * CWn;
    const int w = k & (HWn - 1);                   // ks = w (32 k per word)
    const int c = k >> 4;                          // global c 0..2047
    const float* src = w2 + (size_t)c * Hn + w * 32;
    uint32_t word = 0;
#pragma unroll
    for (int j = 0; j < 32; ++j) word |= (uint32_t)(src[j] > 0.f) << j;
    atomicAdd(&Sw2[c], (int)__popc(word));
    // fragment-major {0,1} bytes: [ks][half][c][16B]
    const int blk = c >> 8, cl = c & 255;
    uint32_t* dst = (uint32_t*)(W2uf + (size_t)blk * 131072);
#pragma unroll
    for (int q = 0; q < 8; ++q) {
      const uint32_t dw = (((word >> (4 * q)) & 0xFu) * 0x00204081u) & 0x01010101u;
      dst[((w * 2 + (q >> 2)) * 256 + cl) * 4 + (q & 3)] = dw;
    }
  }
  if (idx < 8 * Cc)
    thr1[idx] = bn1m[idx] - bn1b[idx] * sqrtf(bn1v[idx] + EPSf) / bn1g[idx];
  if (idx < 8 * Hn) {
    const float th2 = bn2m[idx] - bn2b[idx] * sqrtf(bn2v[idx] + EPSf) / bn2g[idx];
    thr2[idx] = th2;
    int T;
    if (th2 >= 8.0e6f)       T =  (1 << 24);
    else if (th2 <= -8.0e6f) T = -(1 << 24);
    else if (th2 == th2)     T = (int)floorf(th2) + 1;  // strict ceil
    else                     T =  (1 << 24);
    T2i[idx] = T;
    thr3[idx] = bn3m[idx] - bn3b[idx] * sqrtf(bn3v[idx] + EPSf) / bn3g[idx];
    uint32_t dw = 0;
    for (int k2 = 0; k2 < 3; ++k2) dw |= (uint32_t)(dww[(size_t)idx * 3 + k2] > 0.f) << k2;
    dws[idx] = dw;
  }
}

// --------------- K1: bn1 + sign + pack over C  (x -> Xp), i=0 only -----------
__global__ __launch_bounds__(256) void k1_pack(
    const float* __restrict__ resid, const float* __restrict__ thr1,
    uint32_t* __restrict__ Xp)
{
  const int idx = blockIdx.x * 256 + threadIdx.x;  // Bn*CWn*Tn threads
  const int t  = idx & (Tn - 1);
  const int cw = (idx >> 12) & (CWn - 1);
  const int b  = idx >> 15;
  const float* r = resid + ((size_t)(b * Cc + cw * 32)) * Tn + t;
  uint32_t word = 0;
#pragma unroll
  for (int j = 0; j < 32; ++j)
    word |= (uint32_t)(r[(size_t)j * Tn] > thr1[cw * 32 + j]) << j;
  Xp[((size_t)b * CWn + cw) * Tn + t] = word;
}

// --------- K2: binary GEMM1 (C->H) + bn2 + sign + pack over T (-> Y) ---------
// i=0 prologue only (popcount path). Y layout: [b][tw][h].
__global__ __launch_bounds__(256) void k2_gemm1(
    const uint32_t* __restrict__ Xp, const uint32_t* __restrict__ W1p,
    const float* __restrict__ thr2, uint32_t* __restrict__ Y)
{
  const int bid  = blockIdx.x;          // b(16) x og(64) x tblk(16)
  const int tblk = bid & 15;
  const int og   = (bid >> 4) & 63;
  const int b    = bid >> 10;
  const int t    = tblk * 256 + threadIdx.x;
  const int o    = og * 8;

  const uint32_t* xrow = Xp + (size_t)b * CWn * Tn + t;
  const uint32_t* wrow = W1p + o * CWn;     // uniform -> scalar loads
  int acc[8] = {0, 0, 0, 0, 0, 0, 0, 0};
#pragma unroll
  for (int w = 0; w < CWn; ++w) {
    const uint32_t xw = xrow[(size_t)w * Tn];
#pragma unroll
    for (int r = 0; r < 8; ++r)
      acc[r] += __popc(xw ^ wrow[r * CWn + w]);
  }
  const int lane = threadIdx.x & 63;
#pragma unroll
  for (int r = 0; r < 8; ++r) {
    const float v = (float)(Cc - 2 * acc[r]);
    const uint64_t m = __ballot(v > thr2[o + r]);   // bit l <-> lane l
    if ((lane & 31) == 0)
      Y[((size_t)b * TWn + (t >> 5)) * Hn + o + r] = (uint32_t)(m >> lane);
  }
}

// -- K_iter: dwconv_i + MFMA-GEMM2_i + residual + bn1/sign + MFMA-GEMM1_{i+1} --
// Block = 512 threads = (b, 64-t chunk); grid = 1024 blocks.
// Phase A: majority-logic dwconv + bit transpose -> {0,1} bytes Zi8[t][h^swz]
//          (in ZW buffer) + Sz[t] atomics.
// Phase B: wave = 32c-tile; GEMM2 via mfma_i32_32x32x32_i8: A = W2 fragments
//          direct from global (fragment-major, coalesced), B = Zi8 from LDS.
//          dot = 4S - 2Sz(t) - 2Sw2(c) + 512 (exact int); ro = rin + dot;
//          bn1/sign -> Xi8 bytes + Sx[t] atomics.
// Phase C: GEMM1 via MFMA on {0,1} (as r7): W1u staged into ZW (Zi8 dead);
//          integer thresholds; ballot-pack Yout.
__global__ __launch_bounds__(512) void k_iter(
    const uint32_t* __restrict__ Yin, const uint32_t* __restrict__ dws,
    const float* __restrict__ thr3,
    const uint8_t* __restrict__ W2uf, const int* __restrict__ Sw2_i,
    const float* __restrict__ rin, float* __restrict__ rout,
    const float* __restrict__ thr1n,
    const uint8_t* __restrict__ W1u_n, const int* __restrict__ Sw1_n,
    const int* __restrict__ T2i_n, uint32_t* __restrict__ Yout,
    int dil, int do_next)
{
  __shared__ __align__(16) uint8_t ZW[TC * 512];      // 32 KB: Zi8 (A,B) / W1buf (C)
  __shared__ __align__(16) uint8_t Xi8[TC * 256];     // 16 KB {0,1}, [t][c^swz]
  __shared__ int   Tc[Hn];                            // 2 KB
  __shared__ float thr1L[Cc];                         // 1 KB
  __shared__ int   Sw2x2L[Cc];                        // 1 KB
  __shared__ int   Sx[TC], Sz[TC];

  const int chunk = blockIdx.x & (Tn / TC - 1);   // 64 chunks
  const int b     = blockIdx.x >> 6;
  const int tid   = threadIdx.x;
  const int lane  = tid & 63;
  const int wid   = __builtin_amdgcn_readfirstlane(tid >> 6); // 0..7
  const int lh    = lane & 31;
  const int twL   = lane >> 5;
  const int tw0   = chunk * 2;

  if (tid < TC) { Sx[tid] = 0; Sz[tid] = 0; }
  if (tid < Cc) { thr1L[tid] = thr1n[tid]; Sw2x2L[tid] = 2 * Sw2_i[tid]; }
  __syncthreads();

  // ---------------- Phase A: dwconv -> Zi8 bytes + Sz ----------------
#pragma unroll
  for (int task = 0; task < 2; ++task) {
    const int hw = wid * 2 + task;                // 0..15
    const int tw = tw0 + twL;
    const int ch = hw * 32 + lh;

    const uint32_t* yb = Yin + (size_t)b * TWn * Hn + ch;
    const uint32_t ycur = yb[(size_t)tw * Hn];
    uint32_t yl, yr, Vl, Vr;
    if (dil >= 32) {
      const int dw = dil >> 5;
      const bool lok = tw >= dw, rok = tw + dw < TWn;
      yl = lok ? yb[(size_t)(tw - dw) * Hn] : 0u;
      yr = rok ? yb[(size_t)(tw + dw) * Hn] : 0u;
      Vl = lok ? ~0u : 0u;
      Vr = rok ? ~0u : 0u;
    } else {
      const uint32_t yp = (tw > 0) ? yb[(size_t)(tw - 1) * Hn] : 0u;
      const uint32_t yn = (tw < TWn - 1) ? yb[(size_t)(tw + 1) * Hn] : 0u;
      yl = (ycur << dil) | ((tw > 0) ? (yp >> (32 - dil)) : 0u);
      yr = (ycur >> dil) | ((tw < TWn - 1) ? (yn << (32 - dil)) : 0u);
      Vl = (tw == 0) ? (~0u << dil) : ~0u;
      Vr = (tw == TWn - 1) ? (~0u >> dil) : ~0u;
    }
    const uint32_t d = dws[ch];
    const uint32_t a  = ((d & 1u) ? yl : ~yl) & Vl;
    const uint32_t bb = (d & 2u) ? ycur : ~ycur;
    const uint32_t c  = ((d & 4u) ? yr : ~yr) & Vr;

    const float thr = thr3[ch];
    const float v3 = (thr + 3.f) * 0.5f;
    const float v2 = (thr + 2.f) * 0.5f;
    const int K3 = (int)(v3 >= 0.f) + (int)(v3 >= 1.f) + (int)(v3 >= 2.f) + (int)(v3 >= 3.f);
    const int K2 = (int)(v2 >= 0.f) + (int)(v2 >= 1.f) + (int)(v2 >= 2.f);

    const uint32_t g1 = a | bb | c;
    const uint32_t g2 = (a & bb) | (c & (a | bb));
    const uint32_t g3 = a & bb & c;
    const uint32_t full = (K3 == 0) ? ~0u : (K3 == 1) ? g1 : (K3 == 2) ? g2
                        : (K3 == 3) ? g3 : 0u;
    const uint32_t lm = (K2 == 0) ? ~0u : (K2 == 1) ? (bb | c) : (K2 == 2) ? (bb & c) : 0u;
    const uint32_t rm = (K2 == 0) ? ~0u : (K2 == 1) ? (a | bb) : (K2 == 2) ? (a & bb) : 0u;

    uint32_t w = (Vl & Vr & full) | (~Vl & lm) | (~Vr & rm);

    // 32x32 bit transpose within each 32-lane half: lane ends with word for
    // t = lane (local), bit j = channel hw*32+j.
#pragma unroll
    for (int s = 16; s; s >>= 1) {
      const uint32_t m = 0xFFFFFFFFu / ((1u << s) + 1u);
      const uint32_t o = __shfl_xor(w, s, 64);
      w = ((lane & s) == 0) ? ((w & m) | ((o & m) << s))
                            : ((w & ~m) | ((o & ~m) >> s));
    }
    // expand to {0,1} bytes, store swizzled (16B-granular XOR)
    const int swzA = (lane & 15) << 4;
    uint32_t e[8];
#pragma unroll
    for (int q = 0; q < 8; ++q)
      e[q] = (((w >> (4 * q)) & 0xFu) * 0x00204081u) & 0x01010101u;
    i32x4 v0; v0[0] = e[0]; v0[1] = e[1]; v0[2] = e[2]; v0[3] = e[3];
    i32x4 v1; v1[0] = e[4]; v1[1] = e[5]; v1[2] = e[6]; v1[3] = e[7];
    *(i32x4*)&ZW[lane * 512 + ((hw * 32)      ^ swzA)] = v0;
    *(i32x4*)&ZW[lane * 512 + ((hw * 32 + 16) ^ swzA)] = v1;
    atomicAdd(&Sz[lane], (int)__popc(w));
  }
  __syncthreads();

  // ------ Phase B: MFMA GEMM2 (H->C) + residual + bn1/sign ------
  {
    const int mc   = wid;                 // 32-row c-tile
    const int half = lane >> 5;
    const int lrow = mc * 32 + lh;        // A-operand c row
    const int t0   = chunk * TC;

    // residual loads issued up front (coalesced 128B per half-row)
    float rv0[16], rv1[16];
#pragma unroll
    for (int r = 0; r < 16; ++r) {
      const int cr = mc * 32 + (r & 3) + 8 * (r >> 2) + 4 * half;
      const float* rowp = rin + ((size_t)(b * Cc + cr)) * Tn + t0;
      rv0[r] = rowp[lh];
      rv1[r] = rowp[32 + lh];
    }

    const int swz0 = (lh & 15) << 4;      // same for t and t+32
    i32x16 acc0 = {0,0,0,0, 0,0,0,0, 0,0,0,0, 0,0,0,0};
    i32x16 acc1 = {0,0,0,0, 0,0,0,0, 0,0,0,0, 0,0,0,0};
#pragma unroll
    for (int ks = 0; ks < 16; ++ks) {
      const int k0 = ks * 32 + half * 16;
      const i32x4 af  = *(const i32x4*)(W2uf + (((size_t)(ks * 2 + half) * 256 + lrow) * 16));
      const i32x4 bf0 = *(const i32x4*)&ZW[lh * 512 + (k0 ^ swz0)];
      const i32x4 bf1 = *(const i32x4*)&ZW[(32 + lh) * 512 + (k0 ^ swz0)];
      acc0 = __builtin_amdgcn_mfma_i32_32x32x32_i8(af, bf0, acc0, 0, 0, 0);
      acc1 = __builtin_amdgcn_mfma_i32_32x32x32_i8(af, bf1, acc1, 0, 0, 0);
    }

    const int Sz0 = 2 * Sz[lh], Sz1 = 2 * Sz[32 + lh];
    uint32_t dw0[4] = {0,0,0,0}, dw1[4] = {0,0,0,0};
#pragma unroll
    for (int r = 0; r < 16; ++r) {
      const int cr = mc * 32 + (r & 3) + 8 * (r >> 2) + 4 * half;
      const int sw2 = Sw2x2L[cr];
      const float th = thr1L[cr];
      float* orow = rout + ((size_t)(b * Cc + cr)) * Tn + t0;
      const float ro0 = rv0[r] + (float)((acc0[r] << 2) - Sz0 - sw2 + 512);
      const float ro1 = rv1[r] + (float)((acc1[r] << 2) - Sz1 - sw2 + 512);
      orow[lh]      = ro0;
      orow[32 + lh] = ro1;
      dw0[r >> 2] |= (uint32_t)(ro0 > th) << ((r & 3) * 8);
      dw1[r >> 2] |= (uint32_t)(ro1 > th) << ((r & 3) * 8);
    }
    int cnt0 = 0, cnt1 = 0;
#pragma unroll
    for (int g = 0; g < 4; ++g) {
      const int cb = mc * 32 + g * 8 + half * 4;     // 4-aligned; swz bits >=4
      *(uint32_t*)&Xi8[lh * 256 + (cb ^ swz0)]        = dw0[g];
      *(uint32_t*)&Xi8[(32 + lh) * 256 + (cb ^ swz0)] = dw1[g];
      cnt0 += __popc(dw0[g]); cnt1 += __popc(dw1[g]);
    }
    atomicAdd(&Sx[lh], cnt0);
    atomicAdd(&Sx[32 + lh], cnt1);
  }
  __syncthreads();

  // ------ Phase C: MFMA GEMM1 (C->H, {0,1} i8) -> Yout bits ------
  if (do_next) {
    Tc[tid] = T2i_n[tid] + 2 * Sw1_n[tid] - 256;

    const int ntile = wid & 1;                    // which 32-t half
    const int mloc  = wid >> 1;                   // 0..3: 32-row tile in 128
    const int tloc  = ntile * 32 + (lane & 31);
    const int half  = lane >> 5;

    i32x4 bf[8];
#pragma unroll
    for (int ks = 0; ks < 8; ++ks) {
      const int koff = (ks * 32 + half * 16) ^ ((tloc & 15) << 4);
      bf[ks] = *(const i32x4*)&Xi8[tloc * 256 + koff];
    }
    const int Sxv2 = 2 * Sx[tloc];
    uint32_t* yo = Yout + ((size_t)b * TWn + (chunk * 2 + ntile)) * Hn;

#pragma unroll 1
    for (int msup = 0; msup < 4; ++msup) {
      // stage 128x256 {0,1} supertile of W1u into ZW (Zi8 dead now)
      const uint32_t* gsrc = (const uint32_t*)(W1u_n + msup * 32768);
      uint32_t* ldst = (uint32_t*)ZW;
      i32x4 stg[4];
#pragma unroll
      for (int s = 0; s < 4; ++s)
        stg[s] = *(const i32x4*)&gsrc[(s * 512 + tid) * 4];
#pragma unroll
      for (int s = 0; s < 4; ++s)
        *(i32x4*)&ldst[(s * 512 + tid) * 4] = stg[s];
      __syncthreads();

      const int lrow = mloc * 32 + (lane & 31);
      i32x16 acc = {0,0,0,0, 0,0,0,0, 0,0,0,0, 0,0,0,0};
#pragma unroll
      for (int ks = 0; ks < 8; ++ks) {
        const int aoff = (ks * 32 + half * 16) ^ ((lrow & 15) << 4);
        const i32x4 af = *(const i32x4*)&ZW[lrow * 256 + aoff];
        acc = __builtin_amdgcn_mfma_i32_32x32x32_i8(af, bf[ks], acc, 0, 0, 0);
      }

      const int obase = msup * 128 + mloc * 32;
#pragma unroll
      for (int r = 0; r < 16; ++r) {
        const int row = (r & 3) + 8 * (r >> 2) + 4 * half;
        const int o = obase + row;
        const uint64_t m = __ballot((acc[r] << 2) >= Tc[o] + Sxv2);
        if ((lane & 31) == 0) yo[o] = (uint32_t)(m >> lane);
      }
      __syncthreads();
    }
  }
}

// ----------------------------------------------------------------------------
extern "C" void kernel_launch(void* const* d_in, const int* in_sizes, int n_in,
                              void* d_out, int out_size, void* d_ws, size_t ws_size,
                              hipStream_t stream)
{
  const float* x     = (const float*)d_in[0];
  const float* bn1g  = (const float*)d_in[1];
  const float* bn1b  = (const float*)d_in[2];
  const float* bn1m  = (const float*)d_in[3];
  const float* bn1v  = (const float*)d_in[4];
  const float* w1    = (const float*)d_in[5];
  const float* bn2g  = (const float*)d_in[6];
  const float* bn2b  = (const float*)d_in[7];
  const float* bn2m  = (const float*)d_in[8];
  const float* bn2v  = (const float*)d_in[9];
  const float* dww   = (const float*)d_in[10];
  const float* bn3g  = (const float*)d_in[11];
  const float* bn3b  = (const float*)d_in[12];
  const float* bn3m  = (const float*)d_in[13];
  const float* bn3v  = (const float*)d_in[14];
  const float* w2    = (const float*)d_in[15];
  float* out = (float*)d_out;

  // workspace carve-up (~14 MB total)
  char* ws = (char*)d_ws;
  uint32_t* Xp  = (uint32_t*)(ws);                        // 2 MB (prologue)
  uint32_t* Ya  = (uint32_t*)(ws + (2u  << 20));          // 4 MB  [b][tw][h]
  uint32_t* Yb  = (uint32_t*)(ws + (6u  << 20));          // 4 MB  [b][tw][h]
  uint32_t* W1p = (uint32_t*)(ws + (10u << 20));          // 128 KB (packed)
  float*    thr1 = (float*)(ws + (10u << 20) + (256u << 10));   // 8 KB
  float*    thr2 = thr1 + 8 * Cc;                               // 16 KB
  float*    thr3 = thr2 + 8 * Hn;                               // 16 KB
  uint32_t* dws  = (uint32_t*)(thr3 + 8 * Hn);                  // 16 KB
  uint8_t*  W1u  = (uint8_t*)(ws + (11u << 20));          // 1 MB {0,1} swizzled
  int*      Sw1  = (int*)(ws + (12u << 20));              // 16 KB
  int*      Sw2  = (int*)(ws + (12u << 20) + (16u << 10));// 8 KB
  int*      T2i  = (int*)(ws + (12u << 20) + (24u << 10));// 16 KB
  uint8_t*  W2uf = (uint8_t*)(ws + (13u << 20));          // 1 MB fragment-major

  hipMemsetAsync(Sw1, 0, (24u << 10), stream);            // Sw1 + Sw2

  setup_kernel<<<256, 256, 0, stream>>>(bn1g, bn1b, bn1m, bn1v, w1,
                                        bn2g, bn2b, bn2m, bn2v, dww,
                                        bn3g, bn3b, bn3m, bn3v, w2,
                                        thr1, thr2, thr3, dws, W1p,
                                        W1u, Sw1, T2i, W2uf, Sw2);

  k1_pack <<<2048,  256, 0, stream>>>(x, thr1, Xp);
  k2_gemm1<<<16384, 256, 0, stream>>>(Xp, W1p, thr2, Ya);

  for (int i = 0; i < 8; ++i) {
    const float* rin = (i == 0) ? x : out;
    const int inext = (i < 7) ? i + 1 : 7;
    const uint32_t* Yin  = (i & 1) ? Yb : Ya;
    uint32_t*       Yout = (i & 1) ? Ya : Yb;
    k_iter<<<1024, 512, 0, stream>>>(Yin, dws + i * Hn, thr3 + i * Hn,
                                     W2uf + (size_t)i * 131072, Sw2 + i * Cc,
                                     rin, out,
                                     thr1 + inext * Cc,
                                     W1u + (size_t)inext * Hn * 256,
                                     Sw1 + inext * Hn, T2i + inext * Hn,
                                     Yout, 1 << i, (i < 7) ? 1 : 0);
  }
}

// Round 9
// 355.775 us; speedup vs baseline: 1.2300x; 1.0591x over previous
//
#include <hip/hip_runtime.h>
#include <stdint.h>

namespace {
constexpr int Bn  = 16;
constexpr int Cc  = 256;
constexpr int Hn  = 512;
constexpr int Tn  = 4096;
constexpr int CWn = Cc / 32;   // 8 words packed over C
constexpr int HWn = Hn / 32;   // 16 words packed over H
constexpr int TWn = Tn / 32;   // 128 words packed over T
constexpr int TC  = 64;        // t-chunk per fused block
constexpr float EPSf = 1e-5f;
}

typedef __attribute__((ext_vector_type(4)))  int i32x4;
typedef __attribute__((ext_vector_type(16))) int i32x16;

// ---------------- setup: thresholds + packed/unpacked sign weights -----------
// thr = mean - beta*sqrt(var+eps)/gamma  (gamma>=0 => bn(v)>0 <=> v>thr)
// W1f : {0,1} bytes of sign(w1)>0, MFMA-fragment-major [ks(8)][half(2)][h(512)][16B]
//       per repeat-block (128 KB each) -- A-operand read direct from global.
// W2uf: {0,1} bytes of sign(w2)>0, fragment-major [ks(16)][half(2)][c(256)][16B].
// Sw1[h], Sw2[c]: row bit-counts (global atomicAdd, memset-zeroed each call).
// T2i[h]: smallest integer strictly greater than thr2 (inf/NaN clamped).
__global__ __launch_bounds__(256) void setup_kernel(
    const float* __restrict__ bn1g, const float* __restrict__ bn1b,
    const float* __restrict__ bn1m, const float* __restrict__ bn1v,
    const float* __restrict__ w1,
    const float* __restrict__ bn2g, const float* __restrict__ bn2b,
    const float* __restrict__ bn2m, const float* __restrict__ bn2v,
    const float* __restrict__ dww,
    const float* __restrict__ bn3g, const float* __restrict__ bn3b,
    const float* __restrict__ bn3m, const float* __restrict__ bn3v,
    const float* __restrict__ w2,
    float* __restrict__ thr1, float* __restrict__ thr2, float* __restrict__ thr3,
    uint32_t* __restrict__ dws, uint32_t* __restrict__ W1p,
    uint8_t* __restrict__ W1f, int* __restrict__ Sw1, int* __restrict__ T2i,
    uint8_t* __restrict__ W2uf, int* __restrict__ Sw2)
{
  const int idx = blockIdx.x * 256 + threadIdx.x;  // 65536 threads
  if (idx < 8 * Hn * CWn) {                        // W1 words: 32768
    const int w = idx & (CWn - 1);
    const int h = idx >> 3;                        // global h 0..4095
    const float* src = w1 + (size_t)h * Cc + w * 32;
    uint32_t word = 0;
#pragma unroll
    for (int j = 0; j < 32; ++j) word |= (uint32_t)(src[j] > 0.f) << j;
    W1p[h * CWn + w] = word;
    atomicAdd(&Sw1[h], (int)__popc(word));
    // fragment-major {0,1} bytes: [ks=w][half][h_local][16B]
    const int blk = h >> 9, hl = h & 511;
    uint32_t* dst = (uint32_t*)(W1f + (size_t)blk * 131072);
#pragma unroll
    for (int q = 0; q < 8; ++q) {
      const uint32_t dw = (((word >> (4 * q)) & 0xFu) * 0x00204081u) & 0x01010101u;
      dst[((w * 2 + (q >> 2)) * 512 + hl) * 4 + (q & 3)] = dw;
    }
  } else {                                         // W2 words: 32768
    const int k = idx - 8 * Hn * CWn;
    const int w = k & (HWn - 1);                   // ks = w (32 k per word)
    const int c = k >> 4;                          // global c 0..2047
    const float* src = w2 + (size_t)c * Hn + w * 32;
    uint32_t word = 0;
#pragma unroll
    for (int j = 0; j < 32; ++j) word |= (uint32_t)(src[j] > 0.f) << j;
    atomicAdd(&Sw2[c], (int)__popc(word));
    // fragment-major {0,1} bytes: [ks][half][c][16B]
    const int blk = c >> 8, cl = c & 255;
    uint32_t* dst = (uint32_t*)(W2uf + (size_t)blk * 131072);
#pragma unroll
    for (int q = 0; q < 8; ++q) {
      const uint32_t dw = (((word >> (4 * q)) & 0xFu) * 0x00204081u) & 0x01010101u;
      dst[((w * 2 + (q >> 2)) * 256 + cl) * 4 + (q & 3)] = dw;
    }
  }
  if (idx < 8 * Cc)
    thr1[idx] = bn1m[idx] - bn1b[idx] * sqrtf(bn1v[idx] + EPSf) / bn1g[idx];
  if (idx < 8 * Hn) {
    const float th2 = bn2m[idx] - bn2b[idx] * sqrtf(bn2v[idx] + EPSf) / bn2g[idx];
    thr2[idx] = th2;
    int T;
    if (th2 >= 8.0e6f)       T =  (1 << 24);
    else if (th2 <= -8.0e6f) T = -(1 << 24);
    else if (th2 == th2)     T = (int)floorf(th2) + 1;  // strict ceil
    else                     T =  (1 << 24);
    T2i[idx] = T;
    thr3[idx] = bn3m[idx] - bn3b[idx] * sqrtf(bn3v[idx] + EPSf) / bn3g[idx];
    uint32_t dw = 0;
    for (int k2 = 0; k2 < 3; ++k2) dw |= (uint32_t)(dww[(size_t)idx * 3 + k2] > 0.f) << k2;
    dws[idx] = dw;
  }
}

// --------------- K1: bn1 + sign + pack over C  (x -> Xp), i=0 only -----------
__global__ __launch_bounds__(256) void k1_pack(
    const float* __restrict__ resid, const float* __restrict__ thr1,
    uint32_t* __restrict__ Xp)
{
  const int idx = blockIdx.x * 256 + threadIdx.x;  // Bn*CWn*Tn threads
  const int t  = idx & (Tn - 1);
  const int cw = (idx >> 12) & (CWn - 1);
  const int b  = idx >> 15;
  const float* r = resid + ((size_t)(b * Cc + cw * 32)) * Tn + t;
  uint32_t word = 0;
#pragma unroll
  for (int j = 0; j < 32; ++j)
    word |= (uint32_t)(r[(size_t)j * Tn] > thr1[cw * 32 + j]) << j;
  Xp[((size_t)b * CWn + cw) * Tn + t] = word;
}

// --------- K2: binary GEMM1 (C->H) + bn2 + sign + pack over T (-> Y) ---------
// i=0 prologue only (popcount path). Y layout: [b][tw][h].
__global__ __launch_bounds__(256) void k2_gemm1(
    const uint32_t* __restrict__ Xp, const uint32_t* __restrict__ W1p,
    const float* __restrict__ thr2, uint32_t* __restrict__ Y)
{
  const int bid  = blockIdx.x;          // b(16) x og(64) x tblk(16)
  const int tblk = bid & 15;
  const int og   = (bid >> 4) & 63;
  const int b    = bid >> 10;
  const int t    = tblk * 256 + threadIdx.x;
  const int o    = og * 8;

  const uint32_t* xrow = Xp + (size_t)b * CWn * Tn + t;
  const uint32_t* wrow = W1p + o * CWn;     // uniform -> scalar loads
  int acc[8] = {0, 0, 0, 0, 0, 0, 0, 0};
#pragma unroll
  for (int w = 0; w < CWn; ++w) {
    const uint32_t xw = xrow[(size_t)w * Tn];
#pragma unroll
    for (int r = 0; r < 8; ++r)
      acc[r] += __popc(xw ^ wrow[r * CWn + w]);
  }
  const int lane = threadIdx.x & 63;
#pragma unroll
  for (int r = 0; r < 8; ++r) {
    const float v = (float)(Cc - 2 * acc[r]);
    const uint64_t m = __ballot(v > thr2[o + r]);   // bit l <-> lane l
    if ((lane & 31) == 0)
      Y[((size_t)b * TWn + (t >> 5)) * Hn + o + r] = (uint32_t)(m >> lane);
  }
}

// -- K_iter: dwconv_i + MFMA-GEMM2_i + residual + bn1/sign + MFMA-GEMM1_{i+1} --
// Block = 512 threads = (b, 64-t chunk); grid = 1024 blocks; 3 barriers total.
// Phase A: majority-logic dwconv + bit transpose -> {0,1} bytes Zi8[t][h^swz]
//          + Sz[t] (register-accumulated, one atomic).
// Phase B: wave = 32c-tile; GEMM2 via mfma_i32_32x32x32_i8; A = W2 fragments
//          direct from global (8-deep prefetch), B = Zi8 from LDS.
//          dot = 4S - 2Sz(t) - 2Sw2(c) + 512 (exact int); ro = rin + dot;
//          bn1/sign -> Xi8 bytes + Sx[t] atomics.
// Phase C: GEMM1 via MFMA; A = W1 fragments DIRECT FROM GLOBAL (no LDS
//          staging, no internal barriers); integer thresholds; ballot-pack Yout.
__global__ __launch_bounds__(512) void k_iter(
    const uint32_t* __restrict__ Yin, const uint32_t* __restrict__ dws,
    const float* __restrict__ thr3,
    const uint8_t* __restrict__ W2uf, const int* __restrict__ Sw2_i,
    const float* __restrict__ rin, float* __restrict__ rout,
    const float* __restrict__ thr1n,
    const uint8_t* __restrict__ W1f_n, const int* __restrict__ Sw1_n,
    const int* __restrict__ T2i_n, uint32_t* __restrict__ Yout,
    int dil, int do_next)
{
  __shared__ __align__(16) uint8_t Zi8[TC * 512];     // 32 KB {0,1}, [t][h^swz]
  __shared__ __align__(16) uint8_t Xi8[TC * 256];     // 16 KB {0,1}, [t][c^swz]
  __shared__ int   Tc[Hn];                            // 2 KB
  __shared__ float thr1L[Cc];                         // 1 KB
  __shared__ int   Sw2x2L[Cc];                        // 1 KB
  __shared__ int   Sx[TC], Sz[TC];

  const int chunk = blockIdx.x & (Tn / TC - 1);   // 64 chunks
  const int b     = blockIdx.x >> 6;
  const int tid   = threadIdx.x;
  const int lane  = tid & 63;
  const int wid   = __builtin_amdgcn_readfirstlane(tid >> 6); // 0..7
  const int lh    = lane & 31;
  const int twL   = lane >> 5;
  const int tw0   = chunk * 2;

  if (tid < TC) { Sx[tid] = 0; Sz[tid] = 0; }
  if (tid < Cc) { thr1L[tid] = thr1n[tid]; Sw2x2L[tid] = 2 * Sw2_i[tid]; }
  Tc[tid] = T2i_n[tid] + 2 * Sw1_n[tid] - 256;    // tid covers all Hn=512
  __syncthreads();

  // ---------------- Phase A: dwconv -> Zi8 bytes + Sz ----------------
  int zcnt = 0;
#pragma unroll
  for (int task = 0; task < 2; ++task) {
    const int hw = wid * 2 + task;                // 0..15
    const int tw = tw0 + twL;
    const int ch = hw * 32 + lh;

    const uint32_t* yb = Yin + (size_t)b * TWn * Hn + ch;
    const uint32_t ycur = yb[(size_t)tw * Hn];
    uint32_t yl, yr, Vl, Vr;
    if (dil >= 32) {
      const int dw = dil >> 5;
      const bool lok = tw >= dw, rok = tw + dw < TWn;
      yl = lok ? yb[(size_t)(tw - dw) * Hn] : 0u;
      yr = rok ? yb[(size_t)(tw + dw) * Hn] : 0u;
      Vl = lok ? ~0u : 0u;
      Vr = rok ? ~0u : 0u;
    } else {
      const uint32_t yp = (tw > 0) ? yb[(size_t)(tw - 1) * Hn] : 0u;
      const uint32_t yn = (tw < TWn - 1) ? yb[(size_t)(tw + 1) * Hn] : 0u;
      yl = (ycur << dil) | ((tw > 0) ? (yp >> (32 - dil)) : 0u);
      yr = (ycur >> dil) | ((tw < TWn - 1) ? (yn << (32 - dil)) : 0u);
      Vl = (tw == 0) ? (~0u << dil) : ~0u;
      Vr = (tw == TWn - 1) ? (~0u >> dil) : ~0u;
    }
    const uint32_t d = dws[ch];
    const uint32_t a  = ((d & 1u) ? yl : ~yl) & Vl;
    const uint32_t bb = (d & 2u) ? ycur : ~ycur;
    const uint32_t c  = ((d & 4u) ? yr : ~yr) & Vr;

    const float thr = thr3[ch];
    const float v3 = (thr + 3.f) * 0.5f;
    const float v2 = (thr + 2.f) * 0.5f;
    const int K3 = (int)(v3 >= 0.f) + (int)(v3 >= 1.f) + (int)(v3 >= 2.f) + (int)(v3 >= 3.f);
    const int K2 = (int)(v2 >= 0.f) + (int)(v2 >= 1.f) + (int)(v2 >= 2.f);

    const uint32_t g1 = a | bb | c;
    const uint32_t g2 = (a & bb) | (c & (a | bb));
    const uint32_t g3 = a & bb & c;
    const uint32_t full = (K3 == 0) ? ~0u : (K3 == 1) ? g1 : (K3 == 2) ? g2
                        : (K3 == 3) ? g3 : 0u;
    const uint32_t lm = (K2 == 0) ? ~0u : (K2 == 1) ? (bb | c) : (K2 == 2) ? (bb & c) : 0u;
    const uint32_t rm = (K2 == 0) ? ~0u : (K2 == 1) ? (a | bb) : (K2 == 2) ? (a & bb) : 0u;

    uint32_t w = (Vl & Vr & full) | (~Vl & lm) | (~Vr & rm);

    // 32x32 bit transpose within each 32-lane half: lane ends with word for
    // t = lane (local), bit j = channel hw*32+j.
#pragma unroll
    for (int s = 16; s; s >>= 1) {
      const uint32_t m = 0xFFFFFFFFu / ((1u << s) + 1u);
      const uint32_t o = __shfl_xor(w, s, 64);
      w = ((lane & s) == 0) ? ((w & m) | ((o & m) << s))
                            : ((w & ~m) | ((o & ~m) >> s));
    }
    // expand to {0,1} bytes, store swizzled (16B-granular XOR)
    const int swzA = (lane & 15) << 4;
    uint32_t e[8];
#pragma unroll
    for (int q = 0; q < 8; ++q)
      e[q] = (((w >> (4 * q)) & 0xFu) * 0x00204081u) & 0x01010101u;
    i32x4 v0; v0[0] = e[0]; v0[1] = e[1]; v0[2] = e[2]; v0[3] = e[3];
    i32x4 v1; v1[0] = e[4]; v1[1] = e[5]; v1[2] = e[6]; v1[3] = e[7];
    *(i32x4*)&Zi8[lane * 512 + ((hw * 32)      ^ swzA)] = v0;
    *(i32x4*)&Zi8[lane * 512 + ((hw * 32 + 16) ^ swzA)] = v1;
    zcnt += (int)__popc(w);
  }
  atomicAdd(&Sz[lane], zcnt);
  __syncthreads();

  // ------ Phase B: MFMA GEMM2 (H->C) + residual + bn1/sign ------
  {
    const int mc   = wid;                 // 32-row c-tile
    const int half = lane >> 5;
    const int lrow = mc * 32 + lh;        // A-operand c row
    const int t0   = chunk * TC;

    // residual loads issued up front (coalesced 128B per half-row)
    float rv0[16], rv1[16];
#pragma unroll
    for (int r = 0; r < 16; ++r) {
      const int cr = mc * 32 + (r & 3) + 8 * (r >> 2) + 4 * half;
      const float* rowp = rin + ((size_t)(b * Cc + cr)) * Tn + t0;
      rv0[r] = rowp[lh];
      rv1[r] = rowp[32 + lh];
    }

    const int swz0 = (lh & 15) << 4;      // same for t and t+32
    i32x16 acc0 = {0,0,0,0, 0,0,0,0, 0,0,0,0, 0,0,0,0};
    i32x16 acc1 = {0,0,0,0, 0,0,0,0, 0,0,0,0, 0,0,0,0};
#pragma unroll
    for (int kg = 0; kg < 2; ++kg) {
      i32x4 afv[8];
#pragma unroll
      for (int kk = 0; kk < 8; ++kk) {
        const int ks = kg * 8 + kk;
        afv[kk] = *(const i32x4*)(W2uf + (((size_t)(ks * 2 + half) * 256 + lrow) * 16));
      }
#pragma unroll
      for (int kk = 0; kk < 8; ++kk) {
        const int ks = kg * 8 + kk;
        const int k0 = ks * 32 + half * 16;
        const i32x4 bf0 = *(const i32x4*)&Zi8[lh * 512 + (k0 ^ swz0)];
        const i32x4 bf1 = *(const i32x4*)&Zi8[(32 + lh) * 512 + (k0 ^ swz0)];
        acc0 = __builtin_amdgcn_mfma_i32_32x32x32_i8(afv[kk], bf0, acc0, 0, 0, 0);
        acc1 = __builtin_amdgcn_mfma_i32_32x32x32_i8(afv[kk], bf1, acc1, 0, 0, 0);
      }
    }

    const int Sz0 = 2 * Sz[lh], Sz1 = 2 * Sz[32 + lh];
    uint32_t dw0[4] = {0,0,0,0}, dw1[4] = {0,0,0,0};
#pragma unroll
    for (int r = 0; r < 16; ++r) {
      const int cr = mc * 32 + (r & 3) + 8 * (r >> 2) + 4 * half;
      const int sw2 = Sw2x2L[cr];
      const float th = thr1L[cr];
      float* orow = rout + ((size_t)(b * Cc + cr)) * Tn + t0;
      const float ro0 = rv0[r] + (float)((acc0[r] << 2) - Sz0 - sw2 + 512);
      const float ro1 = rv1[r] + (float)((acc1[r] << 2) - Sz1 - sw2 + 512);
      orow[lh]      = ro0;
      orow[32 + lh] = ro1;
      dw0[r >> 2] |= (uint32_t)(ro0 > th) << ((r & 3) * 8);
      dw1[r >> 2] |= (uint32_t)(ro1 > th) << ((r & 3) * 8);
    }
    int cnt0 = 0, cnt1 = 0;
#pragma unroll
    for (int g = 0; g < 4; ++g) {
      const int cb = mc * 32 + g * 8 + half * 4;     // 4-aligned; swz bits >=4
      *(uint32_t*)&Xi8[lh * 256 + (cb ^ swz0)]        = dw0[g];
      *(uint32_t*)&Xi8[(32 + lh) * 256 + (cb ^ swz0)] = dw1[g];
      cnt0 += __popc(dw0[g]); cnt1 += __popc(dw1[g]);
    }
    atomicAdd(&Sx[lh], cnt0);
    atomicAdd(&Sx[32 + lh], cnt1);
  }
  __syncthreads();

  // ------ Phase C: MFMA GEMM1 (C->H, {0,1} i8), W1 direct from global ------
  if (do_next) {
    const int ntile = wid & 1;                    // which 32-t half
    const int mloc  = wid >> 1;                   // 0..3: 32-row tile in 128
    const int tloc  = ntile * 32 + lh;
    const int half  = lane >> 5;

    i32x4 bf[8];
#pragma unroll
    for (int ks = 0; ks < 8; ++ks) {
      const int koff = (ks * 32 + half * 16) ^ ((tloc & 15) << 4);
      bf[ks] = *(const i32x4*)&Xi8[tloc * 256 + koff];
    }
    const int Sxv2 = 2 * Sx[tloc];
    uint32_t* yo = Yout + ((size_t)b * TWn + (chunk * 2 + ntile)) * Hn;

#pragma unroll 1
    for (int msup = 0; msup < 4; ++msup) {
      const int row = msup * 128 + mloc * 32 + lh;   // A-operand h row
      i32x4 afv[8];
#pragma unroll
      for (int ks = 0; ks < 8; ++ks)
        afv[ks] = *(const i32x4*)(W1f_n + (((size_t)(ks * 2 + half) * 512 + row) * 16));
      i32x16 acc = {0,0,0,0, 0,0,0,0, 0,0,0,0, 0,0,0,0};
#pragma unroll
      for (int ks = 0; ks < 8; ++ks)
        acc = __builtin_amdgcn_mfma_i32_32x32x32_i8(afv[ks], bf[ks], acc, 0, 0, 0);

      const int obase = msup * 128 + mloc * 32;
#pragma unroll
      for (int r = 0; r < 16; ++r) {
        const int orow = (r & 3) + 8 * (r >> 2) + 4 * half;
        const int o = obase + orow;
        const uint64_t m = __ballot((acc[r] << 2) >= Tc[o] + Sxv2);
        if ((lane & 31) == 0) yo[o] = (uint32_t)(m >> lane);
      }
    }
  }
}

// ----------------------------------------------------------------------------
extern "C" void kernel_launch(void* const* d_in, const int* in_sizes, int n_in,
                              void* d_out, int out_size, void* d_ws, size_t ws_size,
                              hipStream_t stream)
{
  const float* x     = (const float*)d_in[0];
  const float* bn1g  = (const float*)d_in[1];
  const float* bn1b  = (const float*)d_in[2];
  const float* bn1m  = (const float*)d_in[3];
  const float* bn1v  = (const float*)d_in[4];
  const float* w1    = (const float*)d_in[5];
  const float* bn2g  = (const float*)d_in[6];
  const float* bn2b  = (const float*)d_in[7];
  const float* bn2m  = (const float*)d_in[8];
  const float* bn2v  = (const float*)d_in[9];
  const float* dww   = (const float*)d_in[10];
  const float* bn3g  = (const float*)d_in[11];
  const float* bn3b  = (const float*)d_in[12];
  const float* bn3m  = (const float*)d_in[13];
  const float* bn3v  = (const float*)d_in[14];
  const float* w2    = (const float*)d_in[15];
  float* out = (float*)d_out;

  // workspace carve-up (~14 MB total)
  char* ws = (char*)d_ws;
  uint32_t* Xp  = (uint32_t*)(ws);                        // 2 MB (prologue)
  uint32_t* Ya  = (uint32_t*)(ws + (2u  << 20));          // 4 MB  [b][tw][h]
  uint32_t* Yb  = (uint32_t*)(ws + (6u  << 20));          // 4 MB  [b][tw][h]
  uint32_t* W1p = (uint32_t*)(ws + (10u << 20));          // 128 KB (packed)
  float*    thr1 = (float*)(ws + (10u << 20) + (256u << 10));   // 8 KB
  float*    thr2 = thr1 + 8 * Cc;                               // 16 KB
  float*    thr3 = thr2 + 8 * Hn;                               // 16 KB
  uint32_t* dws  = (uint32_t*)(thr3 + 8 * Hn);                  // 16 KB
  uint8_t*  W1f  = (uint8_t*)(ws + (11u << 20));          // 1 MB fragment-major
  int*      Sw1  = (int*)(ws + (12u << 20));              // 16 KB
  int*      Sw2  = (int*)(ws + (12u << 20) + (16u << 10));// 8 KB
  int*      T2i  = (int*)(ws + (12u << 20) + (24u << 10));// 16 KB
  uint8_t*  W2uf = (uint8_t*)(ws + (13u << 20));          // 1 MB fragment-major

  hipMemsetAsync(Sw1, 0, (24u << 10), stream);            // Sw1 + Sw2

  setup_kernel<<<256, 256, 0, stream>>>(bn1g, bn1b, bn1m, bn1v, w1,
                                        bn2g, bn2b, bn2m, bn2v, dww,
                                        bn3g, bn3b, bn3m, bn3v, w2,
                                        thr1, thr2, thr3, dws, W1p,
                                        W1f, Sw1, T2i, W2uf, Sw2);

  k1_pack <<<2048,  256, 0, stream>>>(x, thr1, Xp);
  k2_gemm1<<<16384, 256, 0, stream>>>(Xp, W1p, thr2, Ya);

  for (int i = 0; i < 8; ++i) {
    const float* rin = (i == 0) ? x : out;
    const int inext = (i < 7) ? i + 1 : 7;
    const uint32_t* Yin  = (i & 1) ? Yb : Ya;
    uint32_t*       Yout = (i & 1) ? Ya : Yb;
    k_iter<<<1024, 512, 0, stream>>>(Yin, dws + i * Hn, thr3 + i * Hn,
                                     W2uf + (size_t)i * 131072, Sw2 + i * Cc,
                                     rin, out,
                                     thr1 + inext * Cc,
                                     W1f + (size_t)inext * 131072,
                                     Sw1 + inext * Hn, T2i + inext * Hn,
                                     Yout, 1 << i, (i < 7) ? 1 : 0);
  }
}